// Round 5
// baseline (783.963 us; speedup 1.0000x reference)
//
#include <hip/hip_runtime.h>

#define N_NODES 50000
#define N_EDGES 800000
#define D_IN    128
#define D_E     64
#define NH      4
#define F_TOT   128          // NH * D_OUT
#define NEG_SLOPE 0.2f
#define NBLK    196          // ceil(N_NODES/256)

typedef __attribute__((ext_vector_type(8))) short short8;   // 8 bf16
typedef __attribute__((ext_vector_type(4))) float f32x4;

__device__ __forceinline__ short f2bf(float x) {            // RNE f32->bf16
    unsigned u = __float_as_uint(x);
    u += 0x7FFFu + ((u >> 16) & 1u);
    return (short)(u >> 16);
}

// exclusive prefix of v across 256 threads (all threads must call)
__device__ __forceinline__ int block_excl_scan_256(int v, int tid) {
    __shared__ int wsum[4];
    const int l = tid & 63, w = tid >> 6;
    int x = v;
#pragma unroll
    for (int off = 1; off < 64; off <<= 1) {
        int t = __shfl_up(x, off, 64);
        if (l >= off) x += t;
    }
    if (l == 63) wsum[w] = x;
    __syncthreads();
    int p = 0;
#pragma unroll
    for (int k = 0; k < 4; ++k) if (k < w) p += wsum[k];
    return p + x - v;
}

// ---------------------------------------------------------------------------
// K1: node transform -> swizzled layout HT_sw[n][s] = HT[n][(s&7)*16+(s>>3)]
// so lane r16 in k_gat reads its 8 features {ft*16+r16} as 2 float4s.
// ---------------------------------------------------------------------------
__global__ __launch_bounds__(256) void k_node_transform(
    const float* __restrict__ H, const float* __restrict__ W,
    float* __restrict__ HTsw)
{
    __shared__ float wt[D_IN * F_TOT];   // wt[k*128+s] = W[f(s)][k]
    const int tid = threadIdx.x;
    for (int i = tid; i < D_IN * F_TOT; i += 256) {
        const int s = i & 127, k = i >> 7;
        const int f = (s & 7) * 16 + (s >> 3);
        wt[k * F_TOT + s] = W[f * D_IN + k];
    }
    __syncthreads();

    const int l = tid & 63;
    const int w = tid >> 6;
    const int gwave  = blockIdx.x * 4 + w;
    const int nwaves = gridDim.x * 4;
    const int ngroups = N_NODES / 8;     // 6250, exact

    for (int grp = gwave; grp < ngroups; grp += nwaves) {
        const int g = grp * 8;
        float ax[8], ay[8];
#pragma unroll
        for (int j = 0; j < 8; ++j) { ax[j] = 0.f; ay[j] = 0.f; }

        for (int k4 = 0; k4 < D_IN / 4; ++k4) {
            float hv[8][4];
#pragma unroll
            for (int j = 0; j < 8; ++j)
                *(float4*)hv[j] = *(const float4*)&H[(size_t)(g + j) * D_IN + k4 * 4];
#pragma unroll
            for (int kk = 0; kk < 4; ++kk) {
                const float2 wk = *(const float2*)&wt[(k4 * 4 + kk) * F_TOT + 2 * l];
#pragma unroll
                for (int j = 0; j < 8; ++j) {
                    ax[j] = fmaf(wk.x, hv[j][kk], ax[j]);
                    ay[j] = fmaf(wk.y, hv[j][kk], ay[j]);
                }
            }
        }
#pragma unroll
        for (int j = 0; j < 8; ++j) {
            float2 r; r.x = ax[j]; r.y = ay[j];
            *(float2*)&HTsw[(size_t)(g + j) * F_TOT + 2 * l] = r;
        }
    }
}

// ---------------------------------------------------------------------------
// K2a: histogram of dst degrees
// ---------------------------------------------------------------------------
__global__ __launch_bounds__(256) void k_hist(
    const int* __restrict__ EI, int* __restrict__ deg)
{
    const int e = blockIdx.x * 256 + threadIdx.x;
    if (e < N_EDGES) atomicAdd(&deg[EI[N_EDGES + e]], 1);
}

// ---------------------------------------------------------------------------
// K2b/c/d: parallel 3-pass exclusive scan of deg (replaces the serial
// single-block scan that was ~100+ us of hidden latency).
// ---------------------------------------------------------------------------
__global__ __launch_bounds__(256) void k_scan_sum(
    const int* __restrict__ deg, int* __restrict__ bsum)
{
    const int tid = threadIdx.x;
    const int i = blockIdx.x * 256 + tid;
    int v = (i < N_NODES) ? deg[i] : 0;
    __shared__ int ws[4];
#pragma unroll
    for (int off = 1; off < 64; off <<= 1) v += __shfl_xor(v, off, 64);
    if ((tid & 63) == 0) ws[tid >> 6] = v;
    __syncthreads();
    if (tid == 0) bsum[blockIdx.x] = ws[0] + ws[1] + ws[2] + ws[3];
}

// single block: scan the 196 block sums; idle lanes convert We -> bf16
__global__ __launch_bounds__(256) void k_scan_block(
    const int* __restrict__ bsum, int* __restrict__ boff,
    const float* __restrict__ We, short* __restrict__ Webf)
{
    const int tid = threadIdx.x;
    const int v = (tid < NBLK) ? bsum[tid] : 0;
    const int e = block_excl_scan_256(v, tid);
    if (tid < NBLK) boff[tid] = e;
    for (int i = tid; i < D_E * F_TOT; i += 256) Webf[i] = f2bf(We[i]);
}

__global__ __launch_bounds__(256) void k_scan_final(
    const int* __restrict__ deg, const int* __restrict__ boff,
    int* __restrict__ row_start, int* __restrict__ cursor)
{
    const int tid = threadIdx.x;
    const int i = blockIdx.x * 256 + tid;
    const int v = (i < N_NODES) ? deg[i] : 0;
    const int e = block_excl_scan_256(v, tid) + boff[blockIdx.x];
    if (i < N_NODES) {
        row_start[i] = e;
        cursor[i] = e;
        if (i == N_NODES - 1) row_start[N_NODES] = e + v;
    }
}

// ---------------------------------------------------------------------------
// K3: CSR permutation + E materialized in CSR order as bf16.
// 4 lanes per edge: each lane converts 16 floats -> 16 bf16 (32B of the
// 128B row). One atomic per edge. Reads coalesced (16 rows/wave = 4KB).
// ---------------------------------------------------------------------------
__global__ __launch_bounds__(256) void k_permute(
    const float* __restrict__ E, const int* __restrict__ EI,
    int* __restrict__ cursor, int* __restrict__ srcperm,
    short* __restrict__ Eperm)
{
    const int tid = threadIdx.x;
    const int l = tid & 63, w = tid >> 6;
    const int q = l & 3;                       // quarter of the row
    const int e = (blockIdx.x * 4 + w) * 16 + (l >> 2);

    const float* ep = &E[(size_t)e * D_E + q * 16];
    const float4 c0 = *(const float4*)ep;
    const float4 c1 = *(const float4*)(ep + 4);
    const float4 c2 = *(const float4*)(ep + 8);
    const float4 c3 = *(const float4*)(ep + 12);
    const int d = EI[N_EDGES + e];

    int pos = 0;
    if (q == 0) pos = atomicAdd(&cursor[d], 1);
    pos = __shfl(pos, l & ~3, 64);
    if (q == 0) srcperm[pos] = EI[e];

    short8 o0, o1;
    o0[0] = f2bf(c0.x); o0[1] = f2bf(c0.y); o0[2] = f2bf(c0.z); o0[3] = f2bf(c0.w);
    o0[4] = f2bf(c1.x); o0[5] = f2bf(c1.y); o0[6] = f2bf(c1.z); o0[7] = f2bf(c1.w);
    o1[0] = f2bf(c2.x); o1[1] = f2bf(c2.y); o1[2] = f2bf(c2.z); o1[3] = f2bf(c2.w);
    o1[4] = f2bf(c3.x); o1[5] = f2bf(c3.y); o1[6] = f2bf(c3.z); o1[7] = f2bf(c3.w);
    *(short8*)&Eperm[(size_t)pos * D_E + q * 16]     = o0;
    *(short8*)&Eperm[(size_t)pos * D_E + q * 16 + 8] = o1;
}

// ---------------------------------------------------------------------------
// K4: fused GAT pass. One wave per dst node; 16-edge tiles.
//   A-frags: two aligned short8 loads from contiguous bf16 Eperm (no
//   indirection, no conversion). B-frags: one dwordx4 from Webf per use.
//   Indices loaded directly per lane (L1 broadcast) -- no shfl on the
//   critical path. Zero atomics.
// ---------------------------------------------------------------------------
__global__ __launch_bounds__(256, 4) void k_gat(
    const short* __restrict__ Eperm, const short* __restrict__ Webf,
    const float* __restrict__ att, const float* __restrict__ HTsw,
    const int* __restrict__ srcperm, const int* __restrict__ row_start,
    float* __restrict__ out)
{
    const int tid = threadIdx.x;
    const int l   = tid & 63;
    const int wv  = tid >> 6;
    const int r16 = l & 15;
    const int g4  = l >> 4;

    // B fragments: bf[ft][kc][j] = We[ft*16+r16][kc*32+g4*8+j] (pre-bf16)
    short8 bf[8][2];
#pragma unroll
    for (int ft = 0; ft < 8; ++ft) {
#pragma unroll
        for (int kc = 0; kc < 2; ++kc)
            bf[ft][kc] = *(const short8*)&Webf[(size_t)(ft * 16 + r16) * D_E + kc * 32 + g4 * 8];
    }
    float attv[8];
#pragma unroll
    for (int ft = 0; ft < 8; ++ft) attv[ft] = att[ft * 16 + r16];

    const int n = blockIdx.x * 4 + wv;
    if (n >= N_NODES) return;
    const int beg = row_start[n];
    const int end = row_start[n + 1];

    float hdv[8];
    {
        const float4 d0 = *(const float4*)&HTsw[(size_t)n * F_TOT + r16 * 8];
        const float4 d1 = *(const float4*)&HTsw[(size_t)n * F_TOT + r16 * 8 + 4];
        hdv[0] = d0.x; hdv[1] = d0.y; hdv[2] = d0.z; hdv[3] = d0.w;
        hdv[4] = d1.x; hdv[5] = d1.y; hdv[6] = d1.z; hdv[7] = d1.w;
    }

    float macc[8];
#pragma unroll
    for (int ft = 0; ft < 8; ++ft) macc[ft] = 0.f;
    float sw4[4] = {0.f, 0.f, 0.f, 0.f};

    for (int base = beg; base < end; base += 16) {
        // A fragment row = edge (base + r16), clamped to beg for tail slots
        int ra = base + r16; ra = ra < end ? ra : beg;
        const short* ep = &Eperm[(size_t)ra * D_E + g4 * 8];
        const short8 af0 = *(const short8*)ep;          // k chunk 0
        const short8 af1 = *(const short8*)(ep + 32);   // k chunk 1

        // src indices for this group's 4 edge rows (L1-broadcast loads)
        int sidx[4];
#pragma unroll
        for (int r = 0; r < 4; ++r) {
            const int ii = base + g4 * 4 + r;
            sidx[r] = srcperm[ii < end ? ii : beg];
        }
        float4 h0[4], h1[4];
#pragma unroll
        for (int r = 0; r < 4; ++r) {
            const float* hp = &HTsw[(size_t)sidx[r] * F_TOT + r16 * 8];
            h0[r] = *(const float4*)hp;
            h1[r] = *(const float4*)(hp + 4);
        }

        f32x4 acc[8];
#pragma unroll
        for (int ft = 0; ft < 8; ++ft) {
            f32x4 z = {0.f, 0.f, 0.f, 0.f};
            z = __builtin_amdgcn_mfma_f32_16x16x32_bf16(af0, bf[ft][0], z, 0, 0, 0);
            acc[ft] = __builtin_amdgcn_mfma_f32_16x16x32_bf16(af1, bf[ft][1], z, 0, 0, 0);
        }

#pragma unroll
        for (int r = 0; r < 4; ++r) {
            const bool valid = (base + g4 * 4 + r) < end;
            float hsv[8];
            hsv[0] = h0[r].x; hsv[1] = h0[r].y; hsv[2] = h0[r].z; hsv[3] = h0[r].w;
            hsv[4] = h1[r].x; hsv[5] = h1[r].y; hsv[6] = h1[r].z; hsv[7] = h1[r].w;
            float ph[4] = {0.f, 0.f, 0.f, 0.f};
#pragma unroll
            for (int ft = 0; ft < 8; ++ft) {
                float v = hsv[ft] + hdv[ft] + acc[ft][r];
                v = v > 0.f ? v : NEG_SLOPE * v;
                ph[ft >> 1] = fmaf(v, attv[ft], ph[ft >> 1]);
            }
#pragma unroll
            for (int m = 1; m < 16; m <<= 1) {
#pragma unroll
                for (int hh = 0; hh < 4; ++hh)
                    ph[hh] += __shfl_xor(ph[hh], m, 64);
            }
            float wgt[4];
#pragma unroll
            for (int hh = 0; hh < 4; ++hh)
                wgt[hh] = valid ? __expf(ph[hh]) : 0.f;
#pragma unroll
            for (int ft = 0; ft < 8; ++ft)
                macc[ft] = fmaf(wgt[ft >> 1], hsv[ft], macc[ft]);
#pragma unroll
            for (int hh = 0; hh < 4; ++hh) sw4[hh] += wgt[hh];
        }
    }

    // cross-group (4x16-lane) reduction: features align across groups
#pragma unroll
    for (int mask = 16; mask < 64; mask <<= 1) {
#pragma unroll
        for (int ft = 0; ft < 8; ++ft) macc[ft] += __shfl_xor(macc[ft], mask, 64);
#pragma unroll
        for (int hh = 0; hh < 4; ++hh) sw4[hh] += __shfl_xor(sw4[hh], mask, 64);
    }
    const float inv = 1.f / (sw4[g4] + 1e-16f);   // group g4 stores head g4's cols
    const int f0 = (2 * g4) * 16 + r16;
    out[(size_t)n * F_TOT + f0]      = macc[2 * g4]     * inv;
    out[(size_t)n * F_TOT + f0 + 16] = macc[2 * g4 + 1] * inv;
}

extern "C" void kernel_launch(void* const* d_in, const int* in_sizes, int n_in,
                              void* d_out, int out_size, void* d_ws, size_t ws_size,
                              hipStream_t stream)
{
    const float* H   = (const float*)d_in[0];
    const int*   EI  = (const int*)d_in[1];
    const float* E   = (const float*)d_in[2];
    const float* W   = (const float*)d_in[3];
    const float* We  = (const float*)d_in[4];
    const float* att = (const float*)d_in[5];
    float* out = (float*)d_out;

    // workspace layout (~132 MB)
    float* HTsw      = (float*)d_ws;                            // 6.4M f32
    short* Eperm     = (short*)(HTsw + (size_t)N_NODES * F_TOT);// 51.2M bf16
    short* Webf      = Eperm + (size_t)N_EDGES * D_E;           // 8192 bf16
    int*   srcperm   = (int*)(Webf + D_E * F_TOT);              // 800k i32
    int*   deg       = srcperm + N_EDGES;                       // 50k
    int*   row_start = deg + N_NODES;                           // 50k+1
    int*   cursor    = row_start + N_NODES + 1;                 // 50k
    int*   bsum      = cursor + N_NODES;                        // 196
    int*   boff      = bsum + NBLK;                             // 196

    hipMemsetAsync(deg, 0, N_NODES * sizeof(int), stream);

    k_hist<<<(N_EDGES + 255) / 256, 256, 0, stream>>>(EI, deg);
    k_scan_sum<<<NBLK, 256, 0, stream>>>(deg, bsum);
    k_scan_block<<<1, 256, 0, stream>>>(bsum, boff, We, Webf);
    k_scan_final<<<NBLK, 256, 0, stream>>>(deg, boff, row_start, cursor);
    k_node_transform<<<512, 256, 0, stream>>>(H, W, HTsw);
    k_permute<<<N_EDGES / 64, 256, 0, stream>>>(E, EI, cursor, srcperm, Eperm);
    k_gat<<<(N_NODES + 3) / 4, 256, 0, stream>>>(Eperm, Webf, att, HTsw,
                                                 srcperm, row_start, out);
}